// Round 1
// baseline (106.507 us; speedup 1.0000x reference)
//
#include <hip/hip_runtime.h>
#include <math.h>

// SSIM loss: probs = sigmoid(logits); 5 depthwise 11x11 Gaussian convs
// (separable), SSIM map, global mean -> scalar 1 - mean(ssim).
//
// Tile design: 32x32 outputs/block, halo 5 -> 42x42 staged inputs.
// LDS: sp/sg 42x44 f32 (pad to 44 to keep stores/loads conflict-light),
// five horizontal-conv intermediates 42x32 f32, ~43 KB total -> 3 blocks/CU.

#define TILE 32
#define HALO 5
#define INW (TILE + 2 * HALO) // 42
#define KW 11

static constexpr int IMG_H = 512;
static constexpr int IMG_W = 512;
static constexpr float kC1 = 0.0001f;   // 0.01^2
static constexpr float kC2 = 0.0009f;   // 0.03^2

__global__ __launch_bounds__(256) void ssim_main_kernel(
    const float* __restrict__ logits,
    const float* __restrict__ gts,
    const float* __restrict__ window, // [11*11], outer(g,g)
    float* __restrict__ partial)      // [gridDim.x]
{
    __shared__ float sp[INW][INW + 2]; // 42 x 44
    __shared__ float sg[INW][INW + 2];
    __shared__ float h1[INW][TILE];
    __shared__ float h2[INW][TILE];
    __shared__ float h11[INW][TILE];
    __shared__ float h22[INW][TILE];
    __shared__ float h12[INW][TILE];
    __shared__ float wg[KW];
    __shared__ float red[256];

    const int tid = threadIdx.x;

    // 1D gaussian = row sums of the 2D window (rows sum to g[i] since sum(g)=1)
    if (tid < KW) {
        float s = 0.f;
#pragma unroll
        for (int j = 0; j < KW; ++j) s += window[tid * KW + j];
        wg[tid] = s;
    }

    const int tiles_x = IMG_W / TILE;            // 16
    const int tiles_per_img = tiles_x * (IMG_H / TILE); // 256
    const int n  = blockIdx.x / tiles_per_img;
    const int t  = blockIdx.x % tiles_per_img;
    const int ty = t / tiles_x;
    const int tx = t % tiles_x;
    const int y0 = ty * TILE - HALO;
    const int x0 = tx * TILE - HALO;

    const float* __restrict__ L = logits + (size_t)n * IMG_H * IMG_W;
    const float* __restrict__ G = gts    + (size_t)n * IMG_H * IMG_W;

    // ---- stage p = sigmoid(logits), g = gts into LDS (zeros outside image) ----
    for (int i = tid; i < INW * INW; i += 256) {
        const int r = i / INW, c = i % INW;
        const int gy = y0 + r, gx = x0 + c;
        float p = 0.f, g = 0.f;
        if (gy >= 0 && gy < IMG_H && gx >= 0 && gx < IMG_W) {
            const float x = L[gy * IMG_W + gx];
            p = 1.f / (1.f + __expf(-x));
            g = G[gy * IMG_W + gx];
        }
        sp[r][c] = p;
        sg[r][c] = g;
    }
    __syncthreads();

    // ---- horizontal 11-tap pass for all 5 fields ----
    for (int i = tid; i < INW * TILE; i += 256) {
        const int r = i / TILE, c = i % TILE;
        float a1 = 0.f, a2 = 0.f, a11 = 0.f, a22 = 0.f, a12 = 0.f;
#pragma unroll
        for (int k = 0; k < KW; ++k) {
            const float w = wg[k];
            const float p = sp[r][c + k];
            const float g = sg[r][c + k];
            a1  += w * p;
            a2  += w * g;
            a11 += w * p * p;
            a22 += w * g * g;
            a12 += w * p * g;
        }
        h1[r][c] = a1;
        h2[r][c] = a2;
        h11[r][c] = a11;
        h22[r][c] = a22;
        h12[r][c] = a12;
    }
    __syncthreads();

    // ---- vertical 11-tap pass + SSIM map + accumulate ----
    float acc = 0.f;
    for (int i = tid; i < TILE * TILE; i += 256) {
        const int y = i / TILE, x = i % TILE;
        float mu1 = 0.f, mu2 = 0.f, e11 = 0.f, e22 = 0.f, e12 = 0.f;
#pragma unroll
        for (int k = 0; k < KW; ++k) {
            const float w = wg[k];
            mu1 += w * h1[y + k][x];
            mu2 += w * h2[y + k][x];
            e11 += w * h11[y + k][x];
            e22 += w * h22[y + k][x];
            e12 += w * h12[y + k][x];
        }
        const float mu1sq = mu1 * mu1;
        const float mu2sq = mu2 * mu2;
        const float mu12  = mu1 * mu2;
        const float s11 = e11 - mu1sq;
        const float s22 = e22 - mu2sq;
        const float s12 = e12 - mu12;
        const float num = (2.f * mu12 + kC1) * (2.f * s12 + kC2);
        const float den = (mu1sq + mu2sq + kC1) * (s11 + s22 + kC2);
        acc += num / den;
    }

    // ---- block reduction ----
    red[tid] = acc;
    __syncthreads();
    for (int s = 128; s > 0; s >>= 1) {
        if (tid < s) red[tid] += red[tid + s];
        __syncthreads();
    }
    if (tid == 0) partial[blockIdx.x] = red[0];
}

__global__ __launch_bounds__(256) void ssim_finalize_kernel(
    const float* __restrict__ partial, int nparts, double inv_count,
    float* __restrict__ out)
{
    __shared__ double sd[256];
    const int tid = threadIdx.x;
    double s = 0.0;
    for (int i = tid; i < nparts; i += 256) s += (double)partial[i];
    sd[tid] = s;
    __syncthreads();
    for (int st = 128; st > 0; st >>= 1) {
        if (tid < st) sd[tid] += sd[tid + st];
        __syncthreads();
    }
    if (tid == 0) out[0] = (float)(1.0 - sd[0] * inv_count);
}

extern "C" void kernel_launch(void* const* d_in, const int* in_sizes, int n_in,
                              void* d_out, int out_size, void* d_ws, size_t ws_size,
                              hipStream_t stream) {
    const float* logits = (const float*)d_in[0];
    const float* gts    = (const float*)d_in[1];
    const float* window = (const float*)d_in[2];
    float* out = (float*)d_out;

    const int nimg = in_sizes[0] / (IMG_H * IMG_W); // 32
    const int tiles_per_img = (IMG_H / TILE) * (IMG_W / TILE); // 256
    const int nblocks = nimg * tiles_per_img; // 8192

    float* partial = (float*)d_ws; // nblocks floats

    ssim_main_kernel<<<nblocks, 256, 0, stream>>>(logits, gts, window, partial);

    const double inv_count = 1.0 / ((double)nimg * IMG_H * IMG_W);
    ssim_finalize_kernel<<<1, 256, 0, stream>>>(partial, nblocks, inv_count, out);
}

// Round 2
// 79.346 us; speedup vs baseline: 1.3423x; 1.3423x over previous
//
#include <hip/hip_runtime.h>
#include <math.h>

// SSIM loss, separable 11x11 Gaussian, fused single pass + tiny finalize.
// Tile 64(y) x 32(x) outputs per 512-thread block; halo 5 -> 74x42 staged.
// LDS ~79.5 KB -> 2 blocks/CU (16 waves/CU).

#define TX 32
#define TY 64
#define HALO 5
#define INX (TX + 2 * HALO)   // 42
#define INY (TY + 2 * HALO)   // 74
#define HPAD 44               // sp/sg row stride (floats): 176B, 16B-aligned
#define VPAD 36               // h row stride (floats): 144B, 16B-aligned
#define KW 11
#define NT 512

static constexpr int IMG_H = 512;
static constexpr int IMG_W = 512;
static constexpr float kC1 = 0.0001f;   // 0.01^2
static constexpr float kC2 = 0.0009f;   // 0.03^2

__global__ __launch_bounds__(NT, 4) void ssim_main(
    const float* __restrict__ logits,
    const float* __restrict__ gts,
    const float* __restrict__ window,
    float* __restrict__ partial)
{
    __shared__ float sp[INY][HPAD];
    __shared__ float sg[INY][HPAD];
    __shared__ float h1[INY][VPAD];
    __shared__ float h2[INY][VPAD];
    __shared__ float h11[INY][VPAD];
    __shared__ float h22[INY][VPAD];
    __shared__ float h12[INY][VPAD];
    __shared__ float wg[KW];
    __shared__ float red[NT / 64];

    const int tid = threadIdx.x;

    // 1D gaussian = row sums of 2D window (cols of window sum to g since sum(g)=1)
    if (tid < KW) {
        float s = 0.f;
#pragma unroll
        for (int j = 0; j < KW; ++j) s += window[tid * KW + j];
        wg[tid] = s;
    }

    const int tiles_x = IMG_W / TX;          // 16
    const int tiles_y = IMG_H / TY;          // 8
    const int tpi = tiles_x * tiles_y;       // 128
    const int n  = blockIdx.x / tpi;
    const int t  = blockIdx.x % tpi;
    const int ty = t / tiles_x;
    const int tx = t % tiles_x;
    const int y0 = ty * TY - HALO;
    const int x0 = tx * TX - HALO;

    const float* __restrict__ L = logits + (size_t)n * IMG_H * IMG_W;
    const float* __restrict__ G = gts    + (size_t)n * IMG_H * IMG_W;

    // ---- stage p = sigmoid(logits), g = gts (zeros outside image) ----
    for (int i = tid; i < INY * INX; i += NT) {
        const int r = i / INX, c = i - r * INX;
        const int gy = y0 + r, gx = x0 + c;
        float p = 0.f, g = 0.f;
        if (gy >= 0 && gy < IMG_H && gx >= 0 && gx < IMG_W) {
            const float xv = L[gy * IMG_W + gx];
            p = 1.f / (1.f + __expf(-xv));
            g = G[gy * IMG_W + gx];
        }
        sp[r][c] = p;
        sg[r][c] = g;
    }
    __syncthreads();

    // taps into registers (static indices only)
    float w[KW];
#pragma unroll
    for (int k = 0; k < KW; ++k) w[k] = wg[k];

    // ---- horizontal pass: 4 outputs/thread-group via float4 window reads ----
    for (int idx = tid; idx < INY * (TX / 4); idx += NT) {   // 74*8 = 592
        const int r = idx >> 3;
        const int c = (idx & 7) << 2;
        float p[16], g[16];
        {
            float4 t0 = *(const float4*)&sp[r][c];
            float4 t1 = *(const float4*)&sp[r][c + 4];
            float4 t2 = *(const float4*)&sp[r][c + 8];
            float4 t3 = *(const float4*)&sp[r][c + 12];
            p[0]=t0.x; p[1]=t0.y; p[2]=t0.z; p[3]=t0.w;
            p[4]=t1.x; p[5]=t1.y; p[6]=t1.z; p[7]=t1.w;
            p[8]=t2.x; p[9]=t2.y; p[10]=t2.z; p[11]=t2.w;
            p[12]=t3.x; p[13]=t3.y; p[14]=t3.z; p[15]=t3.w;
            float4 u0 = *(const float4*)&sg[r][c];
            float4 u1 = *(const float4*)&sg[r][c + 4];
            float4 u2 = *(const float4*)&sg[r][c + 8];
            float4 u3 = *(const float4*)&sg[r][c + 12];
            g[0]=u0.x; g[1]=u0.y; g[2]=u0.z; g[3]=u0.w;
            g[4]=u1.x; g[5]=u1.y; g[6]=u1.z; g[7]=u1.w;
            g[8]=u2.x; g[9]=u2.y; g[10]=u2.z; g[11]=u2.w;
            g[12]=u3.x; g[13]=u3.y; g[14]=u3.z; g[15]=u3.w;
        }
        float a1[4]  = {0,0,0,0}, a2[4]  = {0,0,0,0};
        float a11[4] = {0,0,0,0}, a22[4] = {0,0,0,0}, a12[4] = {0,0,0,0};
#pragma unroll
        for (int i = 0; i < 14; ++i) {
            const float pi = p[i], gi = g[i];
            const float pp = pi * pi, gg = gi * gi, pg = pi * gi;
#pragma unroll
            for (int j = 0; j < 4; ++j) {
                const int k = i - j;
                if (k >= 0 && k < KW) {
                    const float wk = w[k];
                    a1[j]  += wk * pi;
                    a2[j]  += wk * gi;
                    a11[j] += wk * pp;
                    a22[j] += wk * gg;
                    a12[j] += wk * pg;
                }
            }
        }
        *(float4*)&h1[r][c]  = make_float4(a1[0],  a1[1],  a1[2],  a1[3]);
        *(float4*)&h2[r][c]  = make_float4(a2[0],  a2[1],  a2[2],  a2[3]);
        *(float4*)&h11[r][c] = make_float4(a11[0], a11[1], a11[2], a11[3]);
        *(float4*)&h22[r][c] = make_float4(a22[0], a22[1], a22[2], a22[3]);
        *(float4*)&h12[r][c] = make_float4(a12[0], a12[1], a12[2], a12[3]);
    }
    __syncthreads();

    // ---- vertical pass: 4-deep column per thread, scatter-accumulate ----
    const int x  = tid & 31;          // 0..31
    const int yb = (tid >> 5) << 2;   // 0,4,...,60
    float m1[4]  = {0,0,0,0}, m2[4]  = {0,0,0,0};
    float e11[4] = {0,0,0,0}, e22[4] = {0,0,0,0}, e12[4] = {0,0,0,0};
#pragma unroll
    for (int rr = 0; rr < 14; ++rr) {
        const int hr = yb + rr;
        const float v1  = h1[hr][x];
        const float v2  = h2[hr][x];
        const float v11 = h11[hr][x];
        const float v22 = h22[hr][x];
        const float v12 = h12[hr][x];
#pragma unroll
        for (int j = 0; j < 4; ++j) {
            const int k = rr - j;
            if (k >= 0 && k < KW) {
                const float wk = w[k];
                m1[j]  += wk * v1;
                m2[j]  += wk * v2;
                e11[j] += wk * v11;
                e22[j] += wk * v22;
                e12[j] += wk * v12;
            }
        }
    }

    float acc = 0.f;
#pragma unroll
    for (int j = 0; j < 4; ++j) {
        const float mu1sq = m1[j] * m1[j];
        const float mu2sq = m2[j] * m2[j];
        const float mu12  = m1[j] * m2[j];
        const float s11 = e11[j] - mu1sq;
        const float s22 = e22[j] - mu2sq;
        const float s12 = e12[j] - mu12;
        const float num = (2.f * mu12 + kC1) * (2.f * s12 + kC2);
        const float den = (mu1sq + mu2sq + kC1) * (s11 + s22 + kC2);
        acc += num / den;
    }

    // ---- reduction: wave shuffle, then 8 partials via LDS ----
#pragma unroll
    for (int off = 32; off > 0; off >>= 1) acc += __shfl_xor(acc, off);
    if ((tid & 63) == 0) red[tid >> 6] = acc;
    __syncthreads();
    if (tid == 0) {
        float s = 0.f;
#pragma unroll
        for (int i = 0; i < NT / 64; ++i) s += red[i];
        partial[blockIdx.x] = s;
    }
}

__global__ __launch_bounds__(256) void ssim_finalize(
    const float* __restrict__ partial, int nparts, double inv_count,
    float* __restrict__ out)
{
    __shared__ double sd[256];
    const int tid = threadIdx.x;
    double s = 0.0;
    for (int i = tid; i < nparts; i += 256) s += (double)partial[i];
    sd[tid] = s;
    __syncthreads();
    for (int st = 128; st > 0; st >>= 1) {
        if (tid < st) sd[tid] += sd[tid + st];
        __syncthreads();
    }
    if (tid == 0) out[0] = (float)(1.0 - sd[0] * inv_count);
}

extern "C" void kernel_launch(void* const* d_in, const int* in_sizes, int n_in,
                              void* d_out, int out_size, void* d_ws, size_t ws_size,
                              hipStream_t stream) {
    const float* logits = (const float*)d_in[0];
    const float* gts    = (const float*)d_in[1];
    const float* window = (const float*)d_in[2];
    float* out = (float*)d_out;

    const int nimg = in_sizes[0] / (IMG_H * IMG_W);                // 32
    const int tpi  = (IMG_H / TY) * (IMG_W / TX);                  // 128
    const int nblocks = nimg * tpi;                                // 4096

    float* partial = (float*)d_ws;

    ssim_main<<<nblocks, NT, 0, stream>>>(logits, gts, window, partial);

    const double inv_count = 1.0 / ((double)nimg * IMG_H * IMG_W);
    ssim_finalize<<<1, 256, 0, stream>>>(partial, nblocks, inv_count, out);
}